// Round 1
// baseline (170.157 us; speedup 1.0000x reference)
//
#include <hip/hip_runtime.h>
#include <hip/hip_bf16.h>
#include <cstdint>

typedef __attribute__((ext_vector_type(8))) __bf16 bf16x8;
typedef __attribute__((ext_vector_type(4))) float f32x4;
typedef __attribute__((ext_vector_type(8))) unsigned short u16x8;
typedef __attribute__((ext_vector_type(4))) unsigned short u16x4;

#define NEG_INF (-__builtin_inff())

__device__ __forceinline__ unsigned short f2bf(float f) {
    unsigned int u = __builtin_bit_cast(unsigned int, f);
    u += 0x7FFFu + ((u >> 16) & 1u);
    return (unsigned short)(u >> 16);
}

__device__ __forceinline__ void gload16(const void* g, void* l) {
    __builtin_amdgcn_global_load_lds(
        (__attribute__((address_space(1))) void*)(uintptr_t)g,
        (__attribute__((address_space(3))) void*)(uint32_t)(uintptr_t)l, 16, 0, 0);
}

// ---------------- cast x (f32 -> bf16), 8 elems/thread ----------------
__global__ void cast_x_kernel(const float* __restrict__ x, unsigned short* __restrict__ xb) {
    size_t i = (size_t)blockIdx.x * 256 + threadIdx.x;
    const float4* p = (const float4*)x + i * 2;
    float4 a = p[0], c = p[1];
    u16x8 o;
    o[0] = f2bf(a.x); o[1] = f2bf(a.y); o[2] = f2bf(a.z); o[3] = f2bf(a.w);
    o[4] = f2bf(c.x); o[5] = f2bf(c.y); o[6] = f2bf(c.z); o[7] = f2bf(c.w);
    ((u16x8*)xb)[i] = o;
}

// ------------- transpose+cast weights: Wcat=[Wq;Wk;Wv]^T (3072x1024), Wot (1024x1024) -------------
__global__ void castT_w_kernel(const float* __restrict__ W0, const float* __restrict__ W1,
                               const float* __restrict__ W2, const float* __restrict__ W3,
                               unsigned short* __restrict__ Wcat, unsigned short* __restrict__ Wot) {
    __shared__ float t[32][33];
    int z = blockIdx.z;
    const float* src = (z == 0) ? W0 : (z == 1) ? W1 : (z == 2) ? W2 : W3;
    unsigned short* dst = (z < 3) ? (Wcat + (size_t)z * 1024 * 1024) : Wot;
    int n0 = blockIdx.x * 32, k0 = blockIdx.y * 32;
    int tx = threadIdx.x & 31, ty = threadIdx.x >> 5;
    #pragma unroll
    for (int i = 0; i < 4; ++i) {
        int r = ty + i * 8;
        t[r][tx] = src[(size_t)(k0 + r) * 1024 + n0 + tx];
    }
    __syncthreads();
    #pragma unroll
    for (int i = 0; i < 4; ++i) {
        int r = ty + i * 8;
        dst[(size_t)(n0 + r) * 1024 + k0 + tx] = f2bf(t[tx][r]);
    }
}

// ---------------- fused QKV GEMM: A(4096x1024) * Wcat^T rows -> Q,K row-major; V transposed ----------------
__global__ __launch_bounds__(256, 2)
void gemm_qkv_kernel(const unsigned short* __restrict__ A, const unsigned short* __restrict__ Bt,
                     unsigned short* __restrict__ Qb, unsigned short* __restrict__ Kb,
                     unsigned short* __restrict__ Vtb) {
    __shared__ unsigned short As[128 * 64];
    __shared__ unsigned short Bs[128 * 64];
    const int tid = threadIdx.x;
    const int w = tid >> 6, l = tid & 63;
    const int lr = l & 15, lg = l >> 4;
    const int wr = w >> 1, wc = w & 1;
    const int m0 = blockIdx.y * 128;
    const int n0 = blockIdx.x * 128;
    const int K = 1024;

    f32x4 acc[4][4] = {};

    for (int k0 = 0; k0 < 1024; k0 += 64) {
        #pragma unroll
        for (int p = 0; p < 4; ++p) {
            int seg = p * 4 + w;
            int row = seg * 8 + (l >> 3);
            int c16 = (l & 7) ^ (row & 7);
            gload16(A  + (size_t)(m0 + row) * K + k0 + c16 * 8, &As[seg * 512]);
            gload16(Bt + (size_t)(n0 + row) * K + k0 + c16 * 8, &Bs[seg * 512]);
        }
        __syncthreads();
        #pragma unroll
        for (int ks = 0; ks < 2; ++ks) {
            bf16x8 af[4], bfr[4];
            #pragma unroll
            for (int i = 0; i < 4; ++i) {
                int ra = wr * 64 + i * 16 + lr;
                af[i] = *(const bf16x8*)&As[ra * 64 + (((ks << 2) | lg) ^ (ra & 7)) * 8];
                int rb = wc * 64 + i * 16 + lr;
                bfr[i] = *(const bf16x8*)&Bs[rb * 64 + (((ks << 2) | lg) ^ (rb & 7)) * 8];
            }
            #pragma unroll
            for (int i = 0; i < 4; ++i)
                #pragma unroll
                for (int j = 0; j < 4; ++j)
                    acc[i][j] = __builtin_amdgcn_mfma_f32_16x16x32_bf16(af[i], bfr[j], acc[i][j], 0, 0, 0);
        }
        __syncthreads();
    }

    const int seg = n0 >> 10;        // 0=Q, 1=K, 2=V
    const int n0l = n0 & 1023;
    if (seg < 2) {
        unsigned short* C = (seg == 0) ? Qb : Kb;
        const float sc = (seg == 0) ? 0.125f : 1.0f;   // fold 1/sqrt(64) into Q
        #pragma unroll
        for (int i = 0; i < 4; ++i)
            #pragma unroll
            for (int j = 0; j < 4; ++j) {
                int n = n0l + wc * 64 + j * 16 + lr;
                #pragma unroll
                for (int r = 0; r < 4; ++r) {
                    int m = m0 + wr * 64 + i * 16 + lg * 4 + r;
                    C[(size_t)m * 1024 + n] = f2bf(acc[i][j][r] * sc);
                }
            }
    } else {
        // V transposed: Vt[(b*1024 + n)*2048 + s], m = b*2048+s
        #pragma unroll
        for (int i = 0; i < 4; ++i)
            #pragma unroll
            for (int j = 0; j < 4; ++j) {
                int n = n0l + wc * 64 + j * 16 + lr;
                int mb = m0 + wr * 64 + i * 16 + lg * 4;
                int bb = mb >> 11, s = mb & 2047;
                u16x4 o;
                #pragma unroll
                for (int r = 0; r < 4; ++r) o[r] = f2bf(acc[i][j][r]);
                *(u16x4*)&Vtb[((size_t)(bb * 1024 + n)) * 2048 + s] = o;
            }
    }
}

// ---------------- flash attention (causal), 4 waves x 32 q-rows, KV tiles of 64 ----------------
__global__ __launch_bounds__(256, 2)
void flash_attn_kernel(const unsigned short* __restrict__ Q, const unsigned short* __restrict__ Kg,
                       const unsigned short* __restrict__ Vt, unsigned short* __restrict__ ctx) {
    __shared__ unsigned short Ks[64 * 64];
    __shared__ unsigned short Vs[64 * 64];
    __shared__ unsigned short Ps[4 * 32 * 72];
    const int tid = threadIdx.x, w = tid >> 6, l = tid & 63;
    const int lr = l & 15, lg = l >> 4;
    const int bh = blockIdx.y, b = bh >> 4, h = bh & 15;
    const int q0 = blockIdx.x * 128;
    const int qw = q0 + w * 32;

    // hoist Q fragments into registers (already pre-scaled by 1/8)
    bf16x8 qf[2][2];
    #pragma unroll
    for (int mi = 0; mi < 2; ++mi)
        #pragma unroll
        for (int ks = 0; ks < 2; ++ks)
            qf[mi][ks] = *(const bf16x8*)&Q[(size_t)(b * 2048 + qw + mi * 16 + lr) * 1024 + h * 64 + ks * 32 + lg * 8];

    float mrow[2][4], lrow[2][4];
    f32x4 oacc[2][4] = {};
    #pragma unroll
    for (int mi = 0; mi < 2; ++mi)
        #pragma unroll
        for (int r = 0; r < 4; ++r) { mrow[mi][r] = NEG_INF; lrow[mi][r] = 0.0f; }

    const int ktEnd = (q0 >> 6) + 2;
    for (int kt = 0; kt < ktEnd; ++kt) {
        const int k0 = kt * 64;
        // stage K tile (64 k-rows x 64 d) and Vt tile (64 d-rows x 64 k), swizzled source
        #pragma unroll
        for (int p = 0; p < 2; ++p) {
            int seg = p * 4 + w;
            int row = seg * 8 + (l >> 3);
            int c16 = (l & 7) ^ (row & 7);
            gload16(Kg + (size_t)(b * 2048 + k0 + row) * 1024 + h * 64 + c16 * 8, &Ks[seg * 512]);
            gload16(Vt + (size_t)(b * 1024 + h * 64 + row) * 2048 + k0 + c16 * 8, &Vs[seg * 512]);
        }
        __syncthreads();

        if (k0 <= qw + 31) {   // wave-uniform: this wave has unmasked work in this tile
            // ---- S = Q K^T ----
            f32x4 sf[2][4] = {};
            #pragma unroll
            for (int ks = 0; ks < 2; ++ks) {
                bf16x8 kf[4];
                #pragma unroll
                for (int ni = 0; ni < 4; ++ni) {
                    int rk = ni * 16 + lr;
                    kf[ni] = *(const bf16x8*)&Ks[rk * 64 + (((ks << 2) | lg) ^ (rk & 7)) * 8];
                }
                #pragma unroll
                for (int mi = 0; mi < 2; ++mi)
                    #pragma unroll
                    for (int ni = 0; ni < 4; ++ni)
                        sf[mi][ni] = __builtin_amdgcn_mfma_f32_16x16x32_bf16(qf[mi][ks], kf[ni], sf[mi][ni], 0, 0, 0);
            }
            // ---- causal mask ----
            if (k0 + 63 > qw) {
                #pragma unroll
                for (int mi = 0; mi < 2; ++mi)
                    #pragma unroll
                    for (int ni = 0; ni < 4; ++ni)
                        #pragma unroll
                        for (int r = 0; r < 4; ++r) {
                            int q = qw + mi * 16 + lg * 4 + r;
                            int kc = k0 + ni * 16 + lr;
                            if (kc > q) sf[mi][ni][r] = NEG_INF;
                        }
            }
            // ---- online softmax (rows live across the 16 low lanes) ----
            float av[2][4];
            #pragma unroll
            for (int mi = 0; mi < 2; ++mi)
                #pragma unroll
                for (int r = 0; r < 4; ++r) {
                    float tm = fmaxf(fmaxf(sf[mi][0][r], sf[mi][1][r]), fmaxf(sf[mi][2][r], sf[mi][3][r]));
                    tm = fmaxf(tm, __shfl_xor(tm, 1));
                    tm = fmaxf(tm, __shfl_xor(tm, 2));
                    tm = fmaxf(tm, __shfl_xor(tm, 4));
                    tm = fmaxf(tm, __shfl_xor(tm, 8));
                    float mn = fmaxf(mrow[mi][r], tm);
                    float a = __expf(mrow[mi][r] - mn);
                    float rs = 0.0f;
                    #pragma unroll
                    for (int ni = 0; ni < 4; ++ni) {
                        float pv = __expf(sf[mi][ni][r] - mn);
                        rs += pv;
                        Ps[w * 2304 + (mi * 16 + lg * 4 + r) * 72 + ni * 16 + lr] = f2bf(pv);
                    }
                    rs += __shfl_xor(rs, 1);
                    rs += __shfl_xor(rs, 2);
                    rs += __shfl_xor(rs, 4);
                    rs += __shfl_xor(rs, 8);
                    lrow[mi][r] = lrow[mi][r] * a + rs;
                    mrow[mi][r] = mn;
                    av[mi][r] = a;
                }
            #pragma unroll
            for (int mi = 0; mi < 2; ++mi)
                #pragma unroll
                for (int ni = 0; ni < 4; ++ni)
                    #pragma unroll
                    for (int r = 0; r < 4; ++r)
                        oacc[mi][ni][r] *= av[mi][r];

            asm volatile("" ::: "memory");  // order Ps writes vs PV reads (same wave)

            // ---- O += P * V ----
            #pragma unroll
            for (int ks = 0; ks < 2; ++ks) {
                bf16x8 pa[2], vb[4];
                #pragma unroll
                for (int mi = 0; mi < 2; ++mi)
                    pa[mi] = *(const bf16x8*)&Ps[w * 2304 + (mi * 16 + lr) * 72 + ks * 32 + lg * 8];
                #pragma unroll
                for (int ni = 0; ni < 4; ++ni) {
                    int rv = ni * 16 + lr;
                    vb[ni] = *(const bf16x8*)&Vs[rv * 64 + (((ks << 2) | lg) ^ (rv & 7)) * 8];
                }
                #pragma unroll
                for (int mi = 0; mi < 2; ++mi)
                    #pragma unroll
                    for (int ni = 0; ni < 4; ++ni)
                        oacc[mi][ni] = __builtin_amdgcn_mfma_f32_16x16x32_bf16(pa[mi], vb[ni], oacc[mi][ni], 0, 0, 0);
            }
        }
        __syncthreads();
    }

    // epilogue: ctx = O / l, bf16
    #pragma unroll
    for (int mi = 0; mi < 2; ++mi)
        #pragma unroll
        for (int r = 0; r < 4; ++r) {
            float inv = 1.0f / lrow[mi][r];
            int q = qw + mi * 16 + lg * 4 + r;
            size_t base = (size_t)(b * 2048 + q) * 1024 + h * 64 + lr;
            #pragma unroll
            for (int ni = 0; ni < 4; ++ni)
                ctx[base + ni * 16] = f2bf(oacc[mi][ni][r] * inv);
        }
}

// ---------------- output GEMM: ctx(4096x1024) @ Wo + bo -> f32 ----------------
__global__ __launch_bounds__(256, 2)
void gemm_out_kernel(const unsigned short* __restrict__ A, const unsigned short* __restrict__ Bt,
                     float* __restrict__ C, const float* __restrict__ bias) {
    __shared__ unsigned short As[128 * 64];
    __shared__ unsigned short Bs[128 * 64];
    const int tid = threadIdx.x;
    const int w = tid >> 6, l = tid & 63;
    const int lr = l & 15, lg = l >> 4;
    const int wr = w >> 1, wc = w & 1;
    const int m0 = blockIdx.y * 128;
    const int n0 = blockIdx.x * 128;
    const int K = 1024;

    f32x4 acc[4][4] = {};

    for (int k0 = 0; k0 < 1024; k0 += 64) {
        #pragma unroll
        for (int p = 0; p < 4; ++p) {
            int seg = p * 4 + w;
            int row = seg * 8 + (l >> 3);
            int c16 = (l & 7) ^ (row & 7);
            gload16(A  + (size_t)(m0 + row) * K + k0 + c16 * 8, &As[seg * 512]);
            gload16(Bt + (size_t)(n0 + row) * K + k0 + c16 * 8, &Bs[seg * 512]);
        }
        __syncthreads();
        #pragma unroll
        for (int ks = 0; ks < 2; ++ks) {
            bf16x8 af[4], bfr[4];
            #pragma unroll
            for (int i = 0; i < 4; ++i) {
                int ra = wr * 64 + i * 16 + lr;
                af[i] = *(const bf16x8*)&As[ra * 64 + (((ks << 2) | lg) ^ (ra & 7)) * 8];
                int rb = wc * 64 + i * 16 + lr;
                bfr[i] = *(const bf16x8*)&Bs[rb * 64 + (((ks << 2) | lg) ^ (rb & 7)) * 8];
            }
            #pragma unroll
            for (int i = 0; i < 4; ++i)
                #pragma unroll
                for (int j = 0; j < 4; ++j)
                    acc[i][j] = __builtin_amdgcn_mfma_f32_16x16x32_bf16(af[i], bfr[j], acc[i][j], 0, 0, 0);
        }
        __syncthreads();
    }

    #pragma unroll
    for (int i = 0; i < 4; ++i)
        #pragma unroll
        for (int j = 0; j < 4; ++j) {
            int n = n0 + wc * 64 + j * 16 + lr;
            float bv = bias[n];
            #pragma unroll
            for (int r = 0; r < 4; ++r) {
                int m = m0 + wr * 64 + i * 16 + lg * 4 + r;
                C[(size_t)m * 1024 + n] = acc[i][j][r] + bv;
            }
        }
}

extern "C" void kernel_launch(void* const* d_in, const int* in_sizes, int n_in,
                              void* d_out, int out_size, void* d_ws, size_t ws_size,
                              hipStream_t stream) {
    (void)in_sizes; (void)n_in; (void)out_size; (void)ws_size;
    const float* x  = (const float*)d_in[0];
    const float* Wq = (const float*)d_in[1];
    const float* Wk = (const float*)d_in[2];
    const float* Wv = (const float*)d_in[3];
    const float* Wo = (const float*)d_in[4];
    const float* bo = (const float*)d_in[5];
    float* out = (float*)d_out;

    char* ws = (char*)d_ws;
    const size_t MB = 1024 * 1024;
    unsigned short* xb   = (unsigned short*)(ws);            // 8 MB: x bf16 (4096x1024)
    unsigned short* Wcat = (unsigned short*)(ws + 8  * MB);  // 6 MB: [Wq;Wk;Wv]^T (3072x1024)
    unsigned short* Wot  = (unsigned short*)(ws + 14 * MB);  // 2 MB: Wo^T
    unsigned short* Qb   = (unsigned short*)(ws + 16 * MB);  // 8 MB
    unsigned short* Kb   = (unsigned short*)(ws + 24 * MB);  // 8 MB
    unsigned short* Vtb  = (unsigned short*)(ws + 32 * MB);  // 8 MB: V^T (b,h,d,s)
    unsigned short* Cxb  = (unsigned short*)(ws + 40 * MB);  // 8 MB: ctx bf16

    cast_x_kernel<<<2048, 256, 0, stream>>>(x, xb);
    castT_w_kernel<<<dim3(32, 32, 4), 256, 0, stream>>>(Wq, Wk, Wv, Wo, Wcat, Wot);
    gemm_qkv_kernel<<<dim3(24, 32), 256, 0, stream>>>(xb, Wcat, Qb, Kb, Vtb);
    flash_attn_kernel<<<dim3(16, 32), 256, 0, stream>>>(Qb, Kb, Vtb, Cxb);
    gemm_out_kernel<<<dim3(8, 32), 256, 0, stream>>>(Cxb, Wot, out, bo);
}

// Round 2
// 129.783 us; speedup vs baseline: 1.3111x; 1.3111x over previous
//
#include <hip/hip_runtime.h>
#include <hip/hip_bf16.h>
#include <cstdint>

typedef __attribute__((ext_vector_type(8))) __bf16 bf16x8;
typedef __attribute__((ext_vector_type(4))) float f32x4;
typedef __attribute__((ext_vector_type(8))) unsigned short u16x8;
typedef __attribute__((ext_vector_type(4))) unsigned short u16x4;

#define NEG_INF (-__builtin_inff())

__device__ __forceinline__ unsigned short f2bf(float f) {
    unsigned int u = __builtin_bit_cast(unsigned int, f);
    u += 0x7FFFu + ((u >> 16) & 1u);
    return (unsigned short)(u >> 16);
}

__device__ __forceinline__ void gload16(const void* g, void* l) {
    __builtin_amdgcn_global_load_lds(
        (__attribute__((address_space(1))) void*)(uintptr_t)g,
        (__attribute__((address_space(3))) void*)(uint32_t)(uintptr_t)l, 16, 0, 0);
}

// ---------------- cast x (f32 -> bf16), 8 elems/thread ----------------
__global__ void cast_x_kernel(const float* __restrict__ x, unsigned short* __restrict__ xb) {
    size_t i = (size_t)blockIdx.x * 256 + threadIdx.x;
    const float4* p = (const float4*)x + i * 2;
    float4 a = p[0], c = p[1];
    u16x8 o;
    o[0] = f2bf(a.x); o[1] = f2bf(a.y); o[2] = f2bf(a.z); o[3] = f2bf(a.w);
    o[4] = f2bf(c.x); o[5] = f2bf(c.y); o[6] = f2bf(c.z); o[7] = f2bf(c.w);
    ((u16x8*)xb)[i] = o;
}

// ------------- transpose+cast weights: Wcat=[Wq;Wk;Wv]^T (3072x1024), Wot (1024x1024) -------------
__global__ void castT_w_kernel(const float* __restrict__ W0, const float* __restrict__ W1,
                               const float* __restrict__ W2, const float* __restrict__ W3,
                               unsigned short* __restrict__ Wcat, unsigned short* __restrict__ Wot) {
    __shared__ float t[32][33];
    int z = blockIdx.z;
    const float* src = (z == 0) ? W0 : (z == 1) ? W1 : (z == 2) ? W2 : W3;
    unsigned short* dst = (z < 3) ? (Wcat + (size_t)z * 1024 * 1024) : Wot;
    int n0 = blockIdx.x * 32, k0 = blockIdx.y * 32;
    int tx = threadIdx.x & 31, ty = threadIdx.x >> 5;
    #pragma unroll
    for (int i = 0; i < 4; ++i) {
        int r = ty + i * 8;
        t[r][tx] = src[(size_t)(k0 + r) * 1024 + n0 + tx];
    }
    __syncthreads();
    #pragma unroll
    for (int i = 0; i < 4; ++i) {
        int r = ty + i * 8;
        dst[(size_t)(n0 + r) * 1024 + k0 + tx] = f2bf(t[tx][r]);
    }
}

// ---------------- fused QKV GEMM: A(4096x1024) * Wcat^T rows -> Q,K row-major; V transposed ----------------
__global__ __launch_bounds__(256, 2)
void gemm_qkv_kernel(const unsigned short* __restrict__ A, const unsigned short* __restrict__ Bt,
                     unsigned short* __restrict__ Qb, unsigned short* __restrict__ Kb,
                     unsigned short* __restrict__ Vtb) {
    __shared__ unsigned short As[128 * 64];
    __shared__ unsigned short Bs[128 * 64];
    const int tid = threadIdx.x;
    const int w = tid >> 6, l = tid & 63;
    const int lr = l & 15, lg = l >> 4;
    const int wr = w >> 1, wc = w & 1;
    const int m0 = blockIdx.y * 128;
    const int n0 = blockIdx.x * 128;
    const int K = 1024;

    f32x4 acc[4][4] = {};

    for (int k0 = 0; k0 < 1024; k0 += 64) {
        #pragma unroll
        for (int p = 0; p < 4; ++p) {
            int seg = p * 4 + w;
            int row = seg * 8 + (l >> 3);
            int c16 = (l & 7) ^ (row & 7);
            gload16(A  + (size_t)(m0 + row) * K + k0 + c16 * 8, &As[seg * 512]);
            gload16(Bt + (size_t)(n0 + row) * K + k0 + c16 * 8, &Bs[seg * 512]);
        }
        __syncthreads();
        #pragma unroll
        for (int ks = 0; ks < 2; ++ks) {
            bf16x8 af[4], bfr[4];
            #pragma unroll
            for (int i = 0; i < 4; ++i) {
                int ra = wr * 64 + i * 16 + lr;
                af[i] = *(const bf16x8*)&As[ra * 64 + (((ks << 2) | lg) ^ (ra & 7)) * 8];
                int rb = wc * 64 + i * 16 + lr;
                bfr[i] = *(const bf16x8*)&Bs[rb * 64 + (((ks << 2) | lg) ^ (rb & 7)) * 8];
            }
            #pragma unroll
            for (int i = 0; i < 4; ++i)
                #pragma unroll
                for (int j = 0; j < 4; ++j)
                    acc[i][j] = __builtin_amdgcn_mfma_f32_16x16x32_bf16(af[i], bfr[j], acc[i][j], 0, 0, 0);
        }
        __syncthreads();
    }

    const int seg = n0 >> 10;        // 0=Q, 1=K, 2=V
    const int n0l = n0 & 1023;
    if (seg < 2) {
        unsigned short* C = (seg == 0) ? Qb : Kb;
        // fold 1/sqrt(64) AND log2(e) into Q so attention can use raw exp2
        const float sc = (seg == 0) ? 0.125f * 1.44269504f : 1.0f;
        #pragma unroll
        for (int i = 0; i < 4; ++i)
            #pragma unroll
            for (int j = 0; j < 4; ++j) {
                int n = n0l + wc * 64 + j * 16 + lr;
                #pragma unroll
                for (int r = 0; r < 4; ++r) {
                    int m = m0 + wr * 64 + i * 16 + lg * 4 + r;
                    C[(size_t)m * 1024 + n] = f2bf(acc[i][j][r] * sc);
                }
            }
    } else {
        // V transposed: Vt[(b*1024 + n)*2048 + s], m = b*2048+s
        #pragma unroll
        for (int i = 0; i < 4; ++i)
            #pragma unroll
            for (int j = 0; j < 4; ++j) {
                int n = n0l + wc * 64 + j * 16 + lr;
                int mb = m0 + wr * 64 + i * 16 + lg * 4;
                int bb = mb >> 11, s = mb & 2047;
                u16x4 o;
                #pragma unroll
                for (int r = 0; r < 4; ++r) o[r] = f2bf(acc[i][j][r]);
                *(u16x4*)&Vtb[((size_t)(bb * 1024 + n)) * 2048 + s] = o;
            }
    }
}

// ---------------- flash attention (causal), 4 waves x 16 q-rows, KV tiles of 64 ----------------
// grid: 1024 blocks, decoded so each CU's 4 resident blocks have constant total work
__global__ __launch_bounds__(256, 4)
void flash_attn_kernel(const unsigned short* __restrict__ Q, const unsigned short* __restrict__ Kg,
                       const unsigned short* __restrict__ Vt, unsigned short* __restrict__ ctx) {
    __shared__ unsigned short Ks[64 * 64];
    __shared__ unsigned short Vs[64 * 64];
    __shared__ unsigned short Ps[4 * 16 * 72];
    const int tid = threadIdx.x, w = tid >> 6, l = tid & 63;
    const int lr = l & 15, lg = l >> 4;

    // balanced decode: blocks {k, k+256, k+512, k+768} -> q-slots {g, 15-g, 16+g, 31-g}
    const int id = blockIdx.x;
    const int hi = id >> 8;          // round 0..3
    const int lo = id & 255;
    const int g  = lo >> 5;          // 0..7
    const int bh = lo & 31;
    const int qs = hi * 8 + ((hi & 1) ? (7 - g) : g);
    const int b = bh >> 4, h = bh & 15;
    const int q0 = qs * 64;
    const int qw = q0 + w * 16;

    // hoist Q fragments into registers (pre-scaled by 0.125*log2e)
    bf16x8 qf[2];
    #pragma unroll
    for (int ks = 0; ks < 2; ++ks)
        qf[ks] = *(const bf16x8*)&Q[(size_t)(b * 2048 + qw + lr) * 1024 + h * 64 + ks * 32 + lg * 8];

    float mrow[4], lrow[4];
    f32x4 oacc[4] = {};
    #pragma unroll
    for (int r = 0; r < 4; ++r) { mrow[r] = NEG_INF; lrow[r] = 0.0f; }

    const int ktEnd = qs + 1;
    for (int kt = 0; kt < ktEnd; ++kt) {
        const int k0 = kt * 64;
        // stage K tile (64 k-rows x 64 d) and Vt tile (64 d-rows x 64 k), swizzled source
        #pragma unroll
        for (int p = 0; p < 2; ++p) {
            int seg = p * 4 + w;
            int row = seg * 8 + (l >> 3);
            int c16 = (l & 7) ^ (row & 7);
            gload16(Kg + (size_t)(b * 2048 + k0 + row) * 1024 + h * 64 + c16 * 8, &Ks[seg * 512]);
            gload16(Vt + (size_t)(b * 1024 + h * 64 + row) * 2048 + k0 + c16 * 8, &Vs[seg * 512]);
        }
        __syncthreads();

        // ---- S = Q K^T  (16 q-rows x 64 k-cols) ----
        f32x4 sf[4] = {};
        #pragma unroll
        for (int ks = 0; ks < 2; ++ks) {
            bf16x8 kf[4];
            #pragma unroll
            for (int ni = 0; ni < 4; ++ni) {
                int rk = ni * 16 + lr;
                kf[ni] = *(const bf16x8*)&Ks[rk * 64 + (((ks << 2) | lg) ^ (rk & 7)) * 8];
            }
            #pragma unroll
            for (int ni = 0; ni < 4; ++ni)
                sf[ni] = __builtin_amdgcn_mfma_f32_16x16x32_bf16(qf[ks], kf[ni], sf[ni], 0, 0, 0);
        }
        // ---- causal mask (only the diagonal tile) ----
        if (kt == ktEnd - 1) {
            #pragma unroll
            for (int ni = 0; ni < 4; ++ni)
                #pragma unroll
                for (int r = 0; r < 4; ++r) {
                    int q = qw + lg * 4 + r;
                    int kc = k0 + ni * 16 + lr;
                    if (kc > q) sf[ni][r] = NEG_INF;
                }
        }
        // ---- online softmax (base-2 domain; rows live across the 16 low lanes) ----
        float av[4];
        #pragma unroll
        for (int r = 0; r < 4; ++r) {
            float tm = fmaxf(fmaxf(sf[0][r], sf[1][r]), fmaxf(sf[2][r], sf[3][r]));
            tm = fmaxf(tm, __shfl_xor(tm, 1));
            tm = fmaxf(tm, __shfl_xor(tm, 2));
            tm = fmaxf(tm, __shfl_xor(tm, 4));
            tm = fmaxf(tm, __shfl_xor(tm, 8));
            float mn = fmaxf(mrow[r], tm);
            float a = __builtin_amdgcn_exp2f(mrow[r] - mn);
            float rs = 0.0f;
            #pragma unroll
            for (int ni = 0; ni < 4; ++ni) {
                float pv = __builtin_amdgcn_exp2f(sf[ni][r] - mn);
                rs += pv;
                Ps[w * 1152 + (lg * 4 + r) * 72 + ni * 16 + lr] = f2bf(pv);
            }
            rs += __shfl_xor(rs, 1);
            rs += __shfl_xor(rs, 2);
            rs += __shfl_xor(rs, 4);
            rs += __shfl_xor(rs, 8);
            lrow[r] = lrow[r] * a + rs;
            mrow[r] = mn;
            av[r] = a;
        }
        #pragma unroll
        for (int ni = 0; ni < 4; ++ni)
            #pragma unroll
            for (int r = 0; r < 4; ++r)
                oacc[ni][r] *= av[r];

        asm volatile("" ::: "memory");  // order Ps writes vs PV reads (same wave)

        // ---- O += P * V ----
        #pragma unroll
        for (int ks = 0; ks < 2; ++ks) {
            bf16x8 pa = *(const bf16x8*)&Ps[w * 1152 + lr * 72 + ks * 32 + lg * 8];
            bf16x8 vb[4];
            #pragma unroll
            for (int ni = 0; ni < 4; ++ni) {
                int rv = ni * 16 + lr;
                vb[ni] = *(const bf16x8*)&Vs[rv * 64 + (((ks << 2) | lg) ^ (rv & 7)) * 8];
            }
            #pragma unroll
            for (int ni = 0; ni < 4; ++ni)
                oacc[ni] = __builtin_amdgcn_mfma_f32_16x16x32_bf16(pa, vb[ni], oacc[ni], 0, 0, 0);
        }
        __syncthreads();
    }

    // epilogue: ctx = O / l, bf16
    #pragma unroll
    for (int r = 0; r < 4; ++r) {
        float inv = 1.0f / lrow[r];
        int q = qw + lg * 4 + r;
        size_t base = (size_t)(b * 2048 + q) * 1024 + h * 64 + lr;
        #pragma unroll
        for (int ni = 0; ni < 4; ++ni)
            ctx[base + ni * 16] = f2bf(oacc[ni][r] * inv);
    }
}

// ---------------- output GEMM: ctx(4096x1024) @ Wo + bo -> f32 ----------------
__global__ __launch_bounds__(256, 2)
void gemm_out_kernel(const unsigned short* __restrict__ A, const unsigned short* __restrict__ Bt,
                     float* __restrict__ C, const float* __restrict__ bias) {
    __shared__ unsigned short As[128 * 64];
    __shared__ unsigned short Bs[128 * 64];
    const int tid = threadIdx.x;
    const int w = tid >> 6, l = tid & 63;
    const int lr = l & 15, lg = l >> 4;
    const int wr = w >> 1, wc = w & 1;
    const int m0 = blockIdx.y * 128;
    const int n0 = blockIdx.x * 128;
    const int K = 1024;

    f32x4 acc[4][4] = {};

    for (int k0 = 0; k0 < 1024; k0 += 64) {
        #pragma unroll
        for (int p = 0; p < 4; ++p) {
            int seg = p * 4 + w;
            int row = seg * 8 + (l >> 3);
            int c16 = (l & 7) ^ (row & 7);
            gload16(A  + (size_t)(m0 + row) * K + k0 + c16 * 8, &As[seg * 512]);
            gload16(Bt + (size_t)(n0 + row) * K + k0 + c16 * 8, &Bs[seg * 512]);
        }
        __syncthreads();
        #pragma unroll
        for (int ks = 0; ks < 2; ++ks) {
            bf16x8 af[4], bfr[4];
            #pragma unroll
            for (int i = 0; i < 4; ++i) {
                int ra = wr * 64 + i * 16 + lr;
                af[i] = *(const bf16x8*)&As[ra * 64 + (((ks << 2) | lg) ^ (ra & 7)) * 8];
                int rb = wc * 64 + i * 16 + lr;
                bfr[i] = *(const bf16x8*)&Bs[rb * 64 + (((ks << 2) | lg) ^ (rb & 7)) * 8];
            }
            #pragma unroll
            for (int i = 0; i < 4; ++i)
                #pragma unroll
                for (int j = 0; j < 4; ++j)
                    acc[i][j] = __builtin_amdgcn_mfma_f32_16x16x32_bf16(af[i], bfr[j], acc[i][j], 0, 0, 0);
        }
        __syncthreads();
    }

    #pragma unroll
    for (int i = 0; i < 4; ++i)
        #pragma unroll
        for (int j = 0; j < 4; ++j) {
            int n = n0 + wc * 64 + j * 16 + lr;
            float bv = bias[n];
            #pragma unroll
            for (int r = 0; r < 4; ++r) {
                int m = m0 + wr * 64 + i * 16 + lg * 4 + r;
                C[(size_t)m * 1024 + n] = acc[i][j][r] + bv;
            }
        }
}

extern "C" void kernel_launch(void* const* d_in, const int* in_sizes, int n_in,
                              void* d_out, int out_size, void* d_ws, size_t ws_size,
                              hipStream_t stream) {
    (void)in_sizes; (void)n_in; (void)out_size; (void)ws_size;
    const float* x  = (const float*)d_in[0];
    const float* Wq = (const float*)d_in[1];
    const float* Wk = (const float*)d_in[2];
    const float* Wv = (const float*)d_in[3];
    const float* Wo = (const float*)d_in[4];
    const float* bo = (const float*)d_in[5];
    float* out = (float*)d_out;

    char* ws = (char*)d_ws;
    const size_t MB = 1024 * 1024;
    unsigned short* xb   = (unsigned short*)(ws);            // 8 MB: x bf16 (4096x1024)
    unsigned short* Wcat = (unsigned short*)(ws + 8  * MB);  // 6 MB: [Wq;Wk;Wv]^T (3072x1024)
    unsigned short* Wot  = (unsigned short*)(ws + 14 * MB);  // 2 MB: Wo^T
    unsigned short* Qb   = (unsigned short*)(ws + 16 * MB);  // 8 MB (pre-scaled by 0.125*log2e)
    unsigned short* Kb   = (unsigned short*)(ws + 24 * MB);  // 8 MB
    unsigned short* Vtb  = (unsigned short*)(ws + 32 * MB);  // 8 MB: V^T (b,h,d,s)
    unsigned short* Cxb  = (unsigned short*)(ws + 40 * MB);  // 8 MB: ctx bf16

    cast_x_kernel<<<2048, 256, 0, stream>>>(x, xb);
    castT_w_kernel<<<dim3(32, 32, 4), 256, 0, stream>>>(Wq, Wk, Wv, Wo, Wcat, Wot);
    gemm_qkv_kernel<<<dim3(24, 32), 256, 0, stream>>>(xb, Wcat, Qb, Kb, Vtb);
    flash_attn_kernel<<<1024, 256, 0, stream>>>(Qb, Kb, Vtb, Cxb);
    gemm_out_kernel<<<dim3(8, 32), 256, 0, stream>>>(Cxb, Wot, out, bo);
}

// Round 3
// 121.765 us; speedup vs baseline: 1.3974x; 1.0659x over previous
//
#include <hip/hip_runtime.h>
#include <hip/hip_bf16.h>
#include <cstdint>

typedef __attribute__((ext_vector_type(8))) __bf16 bf16x8;
typedef __attribute__((ext_vector_type(4))) float f32x4;
typedef __attribute__((ext_vector_type(8))) unsigned short u16x8;
typedef __attribute__((ext_vector_type(4))) unsigned short u16x4;

#define NEG_INF (-__builtin_inff())

__device__ __forceinline__ unsigned short f2bf(float f) {
    unsigned int u = __builtin_bit_cast(unsigned int, f);
    u += 0x7FFFu + ((u >> 16) & 1u);
    return (unsigned short)(u >> 16);
}

__device__ __forceinline__ void gload16(const void* g, void* l) {
    __builtin_amdgcn_global_load_lds(
        (__attribute__((address_space(1))) void*)(uintptr_t)g,
        (__attribute__((address_space(3))) void*)(uint32_t)(uintptr_t)l, 16, 0, 0);
}

// ---------------- cast x (f32 -> bf16), 8 elems/thread ----------------
__global__ void cast_x_kernel(const float* __restrict__ x, unsigned short* __restrict__ xb) {
    size_t i = (size_t)blockIdx.x * 256 + threadIdx.x;
    const float4* p = (const float4*)x + i * 2;
    float4 a = p[0], c = p[1];
    u16x8 o;
    o[0] = f2bf(a.x); o[1] = f2bf(a.y); o[2] = f2bf(a.z); o[3] = f2bf(a.w);
    o[4] = f2bf(c.x); o[5] = f2bf(c.y); o[6] = f2bf(c.z); o[7] = f2bf(c.w);
    ((u16x8*)xb)[i] = o;
}

// ------------- transpose+cast weights: Wcat=[Wq;Wk;Wv]^T (3072x1024), Wot (1024x1024) -------------
__global__ void castT_w_kernel(const float* __restrict__ W0, const float* __restrict__ W1,
                               const float* __restrict__ W2, const float* __restrict__ W3,
                               unsigned short* __restrict__ Wcat, unsigned short* __restrict__ Wot) {
    __shared__ float t[32][33];
    int z = blockIdx.z;
    const float* src = (z == 0) ? W0 : (z == 1) ? W1 : (z == 2) ? W2 : W3;
    unsigned short* dst = (z < 3) ? (Wcat + (size_t)z * 1024 * 1024) : Wot;
    int n0 = blockIdx.x * 32, k0 = blockIdx.y * 32;
    int tx = threadIdx.x & 31, ty = threadIdx.x >> 5;
    #pragma unroll
    for (int i = 0; i < 4; ++i) {
        int r = ty + i * 8;
        t[r][tx] = src[(size_t)(k0 + r) * 1024 + n0 + tx];
    }
    __syncthreads();
    #pragma unroll
    for (int i = 0; i < 4; ++i) {
        int r = ty + i * 8;
        dst[(size_t)(n0 + r) * 1024 + k0 + tx] = f2bf(t[tx][r]);
    }
}

// ---------------- fused QKV GEMM: A(4096x1024) * Wcat^T rows -> Q,K row-major; V transposed ----------------
__global__ __launch_bounds__(256, 2)
void gemm_qkv_kernel(const unsigned short* __restrict__ A, const unsigned short* __restrict__ Bt,
                     unsigned short* __restrict__ Qb, unsigned short* __restrict__ Kb,
                     unsigned short* __restrict__ Vtb) {
    __shared__ unsigned short As[128 * 64];
    __shared__ unsigned short Bs[128 * 64];
    const int tid = threadIdx.x;
    const int w = tid >> 6, l = tid & 63;
    const int lr = l & 15, lg = l >> 4;
    const int wr = w >> 1, wc = w & 1;
    const int m0 = blockIdx.y * 128;
    const int n0 = blockIdx.x * 128;
    const int K = 1024;

    f32x4 acc[4][4] = {};

    for (int k0 = 0; k0 < 1024; k0 += 64) {
        #pragma unroll
        for (int p = 0; p < 4; ++p) {
            int seg = p * 4 + w;
            int row = seg * 8 + (l >> 3);
            int c16 = (l & 7) ^ (row & 7);
            gload16(A  + (size_t)(m0 + row) * K + k0 + c16 * 8, &As[seg * 512]);
            gload16(Bt + (size_t)(n0 + row) * K + k0 + c16 * 8, &Bs[seg * 512]);
        }
        __syncthreads();
        #pragma unroll
        for (int ks = 0; ks < 2; ++ks) {
            bf16x8 af[4], bfr[4];
            #pragma unroll
            for (int i = 0; i < 4; ++i) {
                int ra = wr * 64 + i * 16 + lr;
                af[i] = *(const bf16x8*)&As[ra * 64 + (((ks << 2) | lg) ^ (ra & 7)) * 8];
                int rb = wc * 64 + i * 16 + lr;
                bfr[i] = *(const bf16x8*)&Bs[rb * 64 + (((ks << 2) | lg) ^ (rb & 7)) * 8];
            }
            #pragma unroll
            for (int i = 0; i < 4; ++i)
                #pragma unroll
                for (int j = 0; j < 4; ++j)
                    acc[i][j] = __builtin_amdgcn_mfma_f32_16x16x32_bf16(af[i], bfr[j], acc[i][j], 0, 0, 0);
        }
        __syncthreads();
    }

    const int seg = n0 >> 10;        // 0=Q, 1=K, 2=V
    const int n0l = n0 & 1023;
    if (seg < 2) {
        unsigned short* C = (seg == 0) ? Qb : Kb;
        // fold 1/sqrt(64) AND log2(e) into Q so attention can use raw exp2
        const float sc = (seg == 0) ? 0.125f * 1.44269504f : 1.0f;
        #pragma unroll
        for (int i = 0; i < 4; ++i)
            #pragma unroll
            for (int j = 0; j < 4; ++j) {
                int n = n0l + wc * 64 + j * 16 + lr;
                #pragma unroll
                for (int r = 0; r < 4; ++r) {
                    int m = m0 + wr * 64 + i * 16 + lg * 4 + r;
                    C[(size_t)m * 1024 + n] = f2bf(acc[i][j][r] * sc);
                }
            }
    } else {
        // V transposed: Vt[(b*1024 + n)*2048 + s], m = b*2048+s
        #pragma unroll
        for (int i = 0; i < 4; ++i)
            #pragma unroll
            for (int j = 0; j < 4; ++j) {
                int n = n0l + wc * 64 + j * 16 + lr;
                int mb = m0 + wr * 64 + i * 16 + lg * 4;
                int bb = mb >> 11, s = mb & 2047;
                u16x4 o;
                #pragma unroll
                for (int r = 0; r < 4; ++r) o[r] = f2bf(acc[i][j][r]);
                *(u16x4*)&Vtb[((size_t)(bb * 1024 + n)) * 2048 + s] = o;
            }
    }
}

// ---------------- flash attention (causal) v3 ----------------
// 128-thread blocks (2 waves x 16 q-rows, QBLK=32), KVBLK=64.
// K double-buffered + prefetched; raw s_barrier + counted vmcnt (no vmcnt(0) drain).
// Row-sum via MFMA-with-ones (kills shuffle-add chains). Grid 2048 LPT-ordered
// (longest q-slots first) with ~3 refill blocks per CU for load balance.
__global__ __launch_bounds__(128, 3)
void flash_attn_kernel(const unsigned short* __restrict__ Q, const unsigned short* __restrict__ Kg,
                       const unsigned short* __restrict__ Vt, unsigned short* __restrict__ ctx) {
    __shared__ unsigned short Ks[2][4096];
    __shared__ unsigned short Vs[4096];
    __shared__ unsigned short Ps[2][1152];
    const int tid = threadIdx.x, w = tid >> 6, l = tid & 63;
    const int lr = l & 15, lg = l >> 4;

    const int id = blockIdx.x;
    const int qs = 63 - (id >> 5);          // longest blocks launch first (LPT)
    const int bh = id & 31;
    const int b = bh >> 4, h = bh & 15;
    const int qw = qs * 32 + w * 16;
    const int T = (qs >> 1) + 1;

    const int srow8 = w * 8 + (l >> 3);     // staging row within 16-row round
    const int scol  = (l & 7) ^ (srow8 & 7);
    const unsigned short* Kbase = Kg + (size_t)(b * 2048) * 1024 + h * 64;
    const unsigned short* Vbase = Vt + (size_t)(b * 1024 + h * 64) * 2048;

    // Q fragments (pre-scaled by 0.125*log2e)
    bf16x8 qf[2];
    #pragma unroll
    for (int ks = 0; ks < 2; ++ks)
        qf[ks] = *(const bf16x8*)&Q[(size_t)(b * 2048 + qw + lr) * 1024 + h * 64 + ks * 32 + lg * 8];

    const __bf16 one = (__bf16)1.0f;
    const bf16x8 ones = {one, one, one, one, one, one, one, one};

    float mrow[4], lrow[4];
    f32x4 oacc[4] = {};
    #pragma unroll
    for (int r = 0; r < 4; ++r) { mrow[r] = NEG_INF; lrow[r] = 0.0f; }

    // prologue: stage K(0) into buf 0  (4 loads/thread)
    #pragma unroll
    for (int p = 0; p < 4; ++p)
        gload16(Kbase + (size_t)(p * 16 + srow8) * 1024 + scol * 8, &Ks[0][(p * 16 + w * 8) * 64]);

    for (int t = 0; t < T; ++t) {
        const int cur = t & 1;
        const int k0 = t * 64;
        // issue V(t) then K(t+1) (prefetch into other K buffer)
        #pragma unroll
        for (int p = 0; p < 4; ++p)
            gload16(Vbase + (size_t)(p * 16 + srow8) * 2048 + k0 + scol * 8, &Vs[(p * 16 + w * 8) * 64]);
        const int ktn = (t + 1 < T) ? t + 1 : 0;   // dummy reload keeps vmcnt constant
        #pragma unroll
        for (int p = 0; p < 4; ++p)
            gload16(Kbase + (size_t)(ktn * 64 + p * 16 + srow8) * 1024 + scol * 8, &Ks[cur ^ 1][(p * 16 + w * 8) * 64]);

        asm volatile("s_waitcnt vmcnt(8)" ::: "memory");   // K(t) resident (V(t)+K(t+1) in flight)
        __builtin_amdgcn_s_barrier();

        // ---- S = Q K^T  (16 q-rows x 64 k-cols) ----
        f32x4 sf[4] = {};
        #pragma unroll
        for (int ks = 0; ks < 2; ++ks) {
            bf16x8 kf[4];
            #pragma unroll
            for (int ni = 0; ni < 4; ++ni) {
                int rk = ni * 16 + lr;
                kf[ni] = *(const bf16x8*)&Ks[cur][rk * 64 + (((ks << 2) | lg) ^ (rk & 7)) * 8];
            }
            #pragma unroll
            for (int ni = 0; ni < 4; ++ni)
                sf[ni] = __builtin_amdgcn_mfma_f32_16x16x32_bf16(qf[ks], kf[ni], sf[ni], 0, 0, 0);
        }
        // ---- causal mask (diagonal tile only) ----
        if (t == T - 1) {
            #pragma unroll
            for (int ni = 0; ni < 4; ++ni)
                #pragma unroll
                for (int r = 0; r < 4; ++r) {
                    int q = qw + lg * 4 + r;
                    int kc = k0 + ni * 16 + lr;
                    if (kc > q) sf[ni][r] = NEG_INF;
                }
        }
        // ---- online softmax: row max (shuffles); P -> LDS; sum comes from MFMA-ones ----
        float av[4];
        #pragma unroll
        for (int r = 0; r < 4; ++r) {
            float tm = fmaxf(fmaxf(sf[0][r], sf[1][r]), fmaxf(sf[2][r], sf[3][r]));
            tm = fmaxf(tm, __shfl_xor(tm, 1));
            tm = fmaxf(tm, __shfl_xor(tm, 2));
            tm = fmaxf(tm, __shfl_xor(tm, 4));
            tm = fmaxf(tm, __shfl_xor(tm, 8));
            float mn = fmaxf(mrow[r], tm);
            av[r] = __builtin_amdgcn_exp2f(mrow[r] - mn);
            mrow[r] = mn;
            #pragma unroll
            for (int ni = 0; ni < 4; ++ni) {
                float pv = __builtin_amdgcn_exp2f(sf[ni][r] - mn);
                Ps[w][(lg * 4 + r) * 72 + ni * 16 + lr] = f2bf(pv);
            }
        }
        #pragma unroll
        for (int ni = 0; ni < 4; ++ni)
            #pragma unroll
            for (int r = 0; r < 4; ++r)
                oacc[ni][r] *= av[r];

        asm volatile("s_waitcnt vmcnt(4)" ::: "memory");   // V(t) resident (K(t+1) still in flight)
        __builtin_amdgcn_s_barrier();

        // ---- O += P V ; row-sum via ones-fragment MFMA ----
        f32x4 ls = {0.f, 0.f, 0.f, 0.f};
        #pragma unroll
        for (int ks = 0; ks < 2; ++ks) {
            bf16x8 pa = *(const bf16x8*)&Ps[w][lr * 72 + ks * 32 + lg * 8];
            bf16x8 vb[4];
            #pragma unroll
            for (int ni = 0; ni < 4; ++ni) {
                int rv = ni * 16 + lr;
                vb[ni] = *(const bf16x8*)&Vs[rv * 64 + (((ks << 2) | lg) ^ (rv & 7)) * 8];
            }
            ls = __builtin_amdgcn_mfma_f32_16x16x32_bf16(pa, ones, ls, 0, 0, 0);
            #pragma unroll
            for (int ni = 0; ni < 4; ++ni)
                oacc[ni] = __builtin_amdgcn_mfma_f32_16x16x32_bf16(pa, vb[ni], oacc[ni], 0, 0, 0);
        }
        #pragma unroll
        for (int r = 0; r < 4; ++r)
            lrow[r] = lrow[r] * av[r] + ls[r];

        __builtin_amdgcn_s_barrier();   // Vs/Ks[cur] free for next iteration's stage
    }

    // epilogue: ctx = O / l, bf16
    #pragma unroll
    for (int r = 0; r < 4; ++r) {
        float inv = 1.0f / lrow[r];
        int q = qw + lg * 4 + r;
        size_t base = (size_t)(b * 2048 + q) * 1024 + h * 64 + lr;
        #pragma unroll
        for (int ni = 0; ni < 4; ++ni)
            ctx[base + ni * 16] = f2bf(oacc[ni][r] * inv);
    }
}

// ---------------- output GEMM: ctx(4096x1024) @ Wo + bo -> f32 ----------------
__global__ __launch_bounds__(256, 2)
void gemm_out_kernel(const unsigned short* __restrict__ A, const unsigned short* __restrict__ Bt,
                     float* __restrict__ C, const float* __restrict__ bias) {
    __shared__ unsigned short As[128 * 64];
    __shared__ unsigned short Bs[128 * 64];
    const int tid = threadIdx.x;
    const int w = tid >> 6, l = tid & 63;
    const int lr = l & 15, lg = l >> 4;
    const int wr = w >> 1, wc = w & 1;
    const int m0 = blockIdx.y * 128;
    const int n0 = blockIdx.x * 128;
    const int K = 1024;

    f32x4 acc[4][4] = {};

    for (int k0 = 0; k0 < 1024; k0 += 64) {
        #pragma unroll
        for (int p = 0; p < 4; ++p) {
            int seg = p * 4 + w;
            int row = seg * 8 + (l >> 3);
            int c16 = (l & 7) ^ (row & 7);
            gload16(A  + (size_t)(m0 + row) * K + k0 + c16 * 8, &As[seg * 512]);
            gload16(Bt + (size_t)(n0 + row) * K + k0 + c16 * 8, &Bs[seg * 512]);
        }
        __syncthreads();
        #pragma unroll
        for (int ks = 0; ks < 2; ++ks) {
            bf16x8 af[4], bfr[4];
            #pragma unroll
            for (int i = 0; i < 4; ++i) {
                int ra = wr * 64 + i * 16 + lr;
                af[i] = *(const bf16x8*)&As[ra * 64 + (((ks << 2) | lg) ^ (ra & 7)) * 8];
                int rb = wc * 64 + i * 16 + lr;
                bfr[i] = *(const bf16x8*)&Bs[rb * 64 + (((ks << 2) | lg) ^ (rb & 7)) * 8];
            }
            #pragma unroll
            for (int i = 0; i < 4; ++i)
                #pragma unroll
                for (int j = 0; j < 4; ++j)
                    acc[i][j] = __builtin_amdgcn_mfma_f32_16x16x32_bf16(af[i], bfr[j], acc[i][j], 0, 0, 0);
        }
        __syncthreads();
    }

    #pragma unroll
    for (int i = 0; i < 4; ++i)
        #pragma unroll
        for (int j = 0; j < 4; ++j) {
            int n = n0 + wc * 64 + j * 16 + lr;
            float bv = bias[n];
            #pragma unroll
            for (int r = 0; r < 4; ++r) {
                int m = m0 + wr * 64 + i * 16 + lg * 4 + r;
                C[(size_t)m * 1024 + n] = acc[i][j][r] + bv;
            }
        }
}

extern "C" void kernel_launch(void* const* d_in, const int* in_sizes, int n_in,
                              void* d_out, int out_size, void* d_ws, size_t ws_size,
                              hipStream_t stream) {
    (void)in_sizes; (void)n_in; (void)out_size; (void)ws_size;
    const float* x  = (const float*)d_in[0];
    const float* Wq = (const float*)d_in[1];
    const float* Wk = (const float*)d_in[2];
    const float* Wv = (const float*)d_in[3];
    const float* Wo = (const float*)d_in[4];
    const float* bo = (const float*)d_in[5];
    float* out = (float*)d_out;

    char* ws = (char*)d_ws;
    const size_t MB = 1024 * 1024;
    unsigned short* xb   = (unsigned short*)(ws);            // 8 MB: x bf16 (4096x1024)
    unsigned short* Wcat = (unsigned short*)(ws + 8  * MB);  // 6 MB: [Wq;Wk;Wv]^T (3072x1024)
    unsigned short* Wot  = (unsigned short*)(ws + 14 * MB);  // 2 MB: Wo^T
    unsigned short* Qb   = (unsigned short*)(ws + 16 * MB);  // 8 MB (pre-scaled by 0.125*log2e)
    unsigned short* Kb   = (unsigned short*)(ws + 24 * MB);  // 8 MB
    unsigned short* Vtb  = (unsigned short*)(ws + 32 * MB);  // 8 MB: V^T (b,h,d,s)
    unsigned short* Cxb  = (unsigned short*)(ws + 40 * MB);  // 8 MB: ctx bf16

    cast_x_kernel<<<2048, 256, 0, stream>>>(x, xb);
    castT_w_kernel<<<dim3(32, 32, 4), 256, 0, stream>>>(Wq, Wk, Wv, Wo, Wcat, Wot);
    gemm_qkv_kernel<<<dim3(24, 32), 256, 0, stream>>>(xb, Wcat, Qb, Kb, Vtb);
    flash_attn_kernel<<<2048, 128, 0, stream>>>(Qb, Kb, Vtb, Cxb);
    gemm_out_kernel<<<dim3(8, 32), 256, 0, stream>>>(Cxb, Wot, out, bo);
}

// Round 4
// 114.698 us; speedup vs baseline: 1.4835x; 1.0616x over previous
//
#include <hip/hip_runtime.h>
#include <hip/hip_bf16.h>
#include <cstdint>

typedef __attribute__((ext_vector_type(8))) __bf16 bf16x8;
typedef __attribute__((ext_vector_type(4))) float f32x4;
typedef __attribute__((ext_vector_type(8))) unsigned short u16x8;
typedef __attribute__((ext_vector_type(4))) unsigned short u16x4;

#define NEG_INF (-__builtin_inff())

__device__ __forceinline__ unsigned short f2bf(float f) {
    unsigned int u = __builtin_bit_cast(unsigned int, f);
    u += 0x7FFFu + ((u >> 16) & 1u);
    return (unsigned short)(u >> 16);
}

__device__ __forceinline__ void gload16(const void* g, void* l) {
    __builtin_amdgcn_global_load_lds(
        (__attribute__((address_space(1))) void*)(uintptr_t)g,
        (__attribute__((address_space(3))) void*)(uint32_t)(uintptr_t)l, 16, 0, 0);
}

// ---------------- cast x (f32 -> bf16), 8 elems/thread ----------------
__global__ void cast_x_kernel(const float* __restrict__ x, unsigned short* __restrict__ xb) {
    size_t i = (size_t)blockIdx.x * 256 + threadIdx.x;
    const float4* p = (const float4*)x + i * 2;
    float4 a = p[0], c = p[1];
    u16x8 o;
    o[0] = f2bf(a.x); o[1] = f2bf(a.y); o[2] = f2bf(a.z); o[3] = f2bf(a.w);
    o[4] = f2bf(c.x); o[5] = f2bf(c.y); o[6] = f2bf(c.z); o[7] = f2bf(c.w);
    ((u16x8*)xb)[i] = o;
}

// ------------- transpose+cast weights: Wcat=[Wq;Wk;Wv]^T (3072x1024), Wot (1024x1024) -------------
__global__ void castT_w_kernel(const float* __restrict__ W0, const float* __restrict__ W1,
                               const float* __restrict__ W2, const float* __restrict__ W3,
                               unsigned short* __restrict__ Wcat, unsigned short* __restrict__ Wot) {
    __shared__ float t[32][33];
    int z = blockIdx.z;
    const float* src = (z == 0) ? W0 : (z == 1) ? W1 : (z == 2) ? W2 : W3;
    unsigned short* dst = (z < 3) ? (Wcat + (size_t)z * 1024 * 1024) : Wot;
    int n0 = blockIdx.x * 32, k0 = blockIdx.y * 32;
    int tx = threadIdx.x & 31, ty = threadIdx.x >> 5;
    #pragma unroll
    for (int i = 0; i < 4; ++i) {
        int r = ty + i * 8;
        t[r][tx] = src[(size_t)(k0 + r) * 1024 + n0 + tx];
    }
    __syncthreads();
    #pragma unroll
    for (int i = 0; i < 4; ++i) {
        int r = ty + i * 8;
        dst[(size_t)(n0 + r) * 1024 + k0 + tx] = f2bf(t[tx][r]);
    }
}

// ---------------- fused QKV GEMM: A(4096x1024) * Wcat^T rows -> Q,K row-major; V transposed ----------------
__global__ __launch_bounds__(256, 2)
void gemm_qkv_kernel(const unsigned short* __restrict__ A, const unsigned short* __restrict__ Bt,
                     unsigned short* __restrict__ Qb, unsigned short* __restrict__ Kb,
                     unsigned short* __restrict__ Vtb) {
    __shared__ unsigned short As[128 * 64];
    __shared__ unsigned short Bs[128 * 64];
    const int tid = threadIdx.x;
    const int w = tid >> 6, l = tid & 63;
    const int lr = l & 15, lg = l >> 4;
    const int wr = w >> 1, wc = w & 1;
    const int m0 = blockIdx.y * 128;
    const int n0 = blockIdx.x * 128;
    const int K = 1024;

    f32x4 acc[4][4] = {};

    for (int k0 = 0; k0 < 1024; k0 += 64) {
        #pragma unroll
        for (int p = 0; p < 4; ++p) {
            int seg = p * 4 + w;
            int row = seg * 8 + (l >> 3);
            int c16 = (l & 7) ^ (row & 7);
            gload16(A  + (size_t)(m0 + row) * K + k0 + c16 * 8, &As[seg * 512]);
            gload16(Bt + (size_t)(n0 + row) * K + k0 + c16 * 8, &Bs[seg * 512]);
        }
        __syncthreads();
        #pragma unroll
        for (int ks = 0; ks < 2; ++ks) {
            bf16x8 af[4], bfr[4];
            #pragma unroll
            for (int i = 0; i < 4; ++i) {
                int ra = wr * 64 + i * 16 + lr;
                af[i] = *(const bf16x8*)&As[ra * 64 + (((ks << 2) | lg) ^ (ra & 7)) * 8];
                int rb = wc * 64 + i * 16 + lr;
                bfr[i] = *(const bf16x8*)&Bs[rb * 64 + (((ks << 2) | lg) ^ (rb & 7)) * 8];
            }
            #pragma unroll
            for (int i = 0; i < 4; ++i)
                #pragma unroll
                for (int j = 0; j < 4; ++j)
                    acc[i][j] = __builtin_amdgcn_mfma_f32_16x16x32_bf16(af[i], bfr[j], acc[i][j], 0, 0, 0);
        }
        __syncthreads();
    }

    const int seg = n0 >> 10;        // 0=Q, 1=K, 2=V
    const int n0l = n0 & 1023;
    if (seg < 2) {
        unsigned short* C = (seg == 0) ? Qb : Kb;
        // fold 1/sqrt(64) AND log2(e) into Q so attention can use raw exp2
        const float sc = (seg == 0) ? 0.125f * 1.44269504f : 1.0f;
        #pragma unroll
        for (int i = 0; i < 4; ++i)
            #pragma unroll
            for (int j = 0; j < 4; ++j) {
                int n = n0l + wc * 64 + j * 16 + lr;
                #pragma unroll
                for (int r = 0; r < 4; ++r) {
                    int m = m0 + wr * 64 + i * 16 + lg * 4 + r;
                    C[(size_t)m * 1024 + n] = f2bf(acc[i][j][r] * sc);
                }
            }
    } else {
        // V transposed: Vt[(b*1024 + n)*2048 + s], m = b*2048+s
        #pragma unroll
        for (int i = 0; i < 4; ++i)
            #pragma unroll
            for (int j = 0; j < 4; ++j) {
                int n = n0l + wc * 64 + j * 16 + lr;
                int mb = m0 + wr * 64 + i * 16 + lg * 4;
                int bb = mb >> 11, s = mb & 2047;
                u16x4 o;
                #pragma unroll
                for (int r = 0; r < 4; ++r) o[r] = f2bf(acc[i][j][r]);
                *(u16x4*)&Vtb[((size_t)(bb * 1024 + n)) * 2048 + s] = o;
            }
    }
}

// ---------------- flash attention (causal) v4 ----------------
// 256-thread blocks (4 waves x 16 q-rows, QBLK=64), KVBLK=64.
// K double-buffered + prefetched; raw s_barrier + counted vmcnt (never 0 in loop).
// Row-sum via MFMA-with-ones. Grid 1024 = exact full residency (4 blocks/CU);
// block decode pairs complementary q-slots so every CU's 4 blocks sum to T=66.
__global__ __launch_bounds__(256, 4)
void flash_attn_kernel(const unsigned short* __restrict__ Q, const unsigned short* __restrict__ Kg,
                       const unsigned short* __restrict__ Vt, unsigned short* __restrict__ ctx) {
    __shared__ unsigned short Ks[2][4096];
    __shared__ unsigned short Vs[4096];
    __shared__ unsigned short Ps[4][1152];
    const int tid = threadIdx.x, w = tid >> 6, l = tid & 63;
    const int lr = l & 15, lg = l >> 4;

    // decode: ids {c, c+256, c+512, c+768} -> qs {g, 31-g, 8+g, 23-g} (T-sum 66 per CU)
    const int id = blockIdx.x;
    const int s = id >> 5;
    const int bh = id & 31;
    const int g = s & 7, hi = s >> 3;
    const int qs = (hi & 1) ? (31 - (g + (hi >> 1) * 8)) : (g + (hi >> 1) * 8);
    const int b = bh >> 4, h = bh & 15;
    const int qw = qs * 64 + w * 16;
    const int T = qs + 1;

    const int srow8 = w * 8 + (l >> 3);     // row within each 32-row staging round
    const int scol  = (l & 7) ^ (srow8 & 7);
    const unsigned short* Kbase = Kg + (size_t)(b * 2048) * 1024 + h * 64;
    const unsigned short* Vbase = Vt + (size_t)(b * 1024 + h * 64) * 2048;

    // Q fragments (pre-scaled by 0.125*log2e)
    bf16x8 qf[2];
    #pragma unroll
    for (int ks = 0; ks < 2; ++ks)
        qf[ks] = *(const bf16x8*)&Q[(size_t)(b * 2048 + qw + lr) * 1024 + h * 64 + ks * 32 + lg * 8];

    const __bf16 one = (__bf16)1.0f;
    const bf16x8 ones = {one, one, one, one, one, one, one, one};

    float mrow[4], lrow[4];
    f32x4 oacc[4] = {};
    #pragma unroll
    for (int r = 0; r < 4; ++r) { mrow[r] = NEG_INF; lrow[r] = 0.0f; }

    // prologue: stage K(0) into buf 0 (2 loads/thread)
    #pragma unroll
    for (int p = 0; p < 2; ++p)
        gload16(Kbase + (size_t)(p * 32 + srow8) * 1024 + scol * 8, &Ks[0][(p * 32 + w * 8) * 64]);

    for (int t = 0; t < T; ++t) {
        const int cur = t & 1;
        const int k0 = t * 64;
        // issue V(t), then K(t+1) into the other K buffer
        #pragma unroll
        for (int p = 0; p < 2; ++p)
            gload16(Vbase + (size_t)(p * 32 + srow8) * 2048 + k0 + scol * 8, &Vs[(p * 32 + w * 8) * 64]);
        const int ktn = (t + 1 < T) ? t + 1 : 0;   // dummy reload keeps vmcnt pattern constant
        #pragma unroll
        for (int p = 0; p < 2; ++p)
            gload16(Kbase + (size_t)(ktn * 64 + p * 32 + srow8) * 1024 + scol * 8, &Ks[cur ^ 1][(p * 32 + w * 8) * 64]);

        asm volatile("s_waitcnt vmcnt(4)" ::: "memory");   // K(t) resident; V(t)+K(t+1) in flight
        __builtin_amdgcn_s_barrier();

        // ---- S = Q K^T  (16 q-rows x 64 k-cols) ----
        f32x4 sf[4] = {};
        #pragma unroll
        for (int ks = 0; ks < 2; ++ks) {
            bf16x8 kf[4];
            #pragma unroll
            for (int ni = 0; ni < 4; ++ni) {
                int rk = ni * 16 + lr;
                kf[ni] = *(const bf16x8*)&Ks[cur][rk * 64 + (((ks << 2) | lg) ^ (rk & 7)) * 8];
            }
            #pragma unroll
            for (int ni = 0; ni < 4; ++ni)
                sf[ni] = __builtin_amdgcn_mfma_f32_16x16x32_bf16(qf[ks], kf[ni], sf[ni], 0, 0, 0);
        }
        // ---- causal mask (diagonal tile only) ----
        if (t == T - 1) {
            #pragma unroll
            for (int ni = 0; ni < 4; ++ni)
                #pragma unroll
                for (int r = 0; r < 4; ++r) {
                    int q = qw + lg * 4 + r;
                    int kc = k0 + ni * 16 + lr;
                    if (kc > q) sf[ni][r] = NEG_INF;
                }
        }
        // ---- online softmax: row max (shuffles); P -> LDS; sum via MFMA-ones ----
        float av[4];
        #pragma unroll
        for (int r = 0; r < 4; ++r) {
            float tm = fmaxf(fmaxf(sf[0][r], sf[1][r]), fmaxf(sf[2][r], sf[3][r]));
            tm = fmaxf(tm, __shfl_xor(tm, 1));
            tm = fmaxf(tm, __shfl_xor(tm, 2));
            tm = fmaxf(tm, __shfl_xor(tm, 4));
            tm = fmaxf(tm, __shfl_xor(tm, 8));
            float mn = fmaxf(mrow[r], tm);
            av[r] = __builtin_amdgcn_exp2f(mrow[r] - mn);
            mrow[r] = mn;
            #pragma unroll
            for (int ni = 0; ni < 4; ++ni) {
                float pv = __builtin_amdgcn_exp2f(sf[ni][r] - mn);
                Ps[w][(lg * 4 + r) * 72 + ni * 16 + lr] = f2bf(pv);
            }
        }
        #pragma unroll
        for (int ni = 0; ni < 4; ++ni)
            #pragma unroll
            for (int r = 0; r < 4; ++r)
                oacc[ni][r] *= av[r];

        asm volatile("s_waitcnt vmcnt(2)" ::: "memory");   // V(t) resident; K(t+1) in flight
        __builtin_amdgcn_s_barrier();

        // ---- O += P V ; row-sum via ones-fragment MFMA ----
        f32x4 ls = {0.f, 0.f, 0.f, 0.f};
        #pragma unroll
        for (int ks = 0; ks < 2; ++ks) {
            bf16x8 pa = *(const bf16x8*)&Ps[w][lr * 72 + ks * 32 + lg * 8];
            bf16x8 vb[4];
            #pragma unroll
            for (int ni = 0; ni < 4; ++ni) {
                int rv = ni * 16 + lr;
                vb[ni] = *(const bf16x8*)&Vs[rv * 64 + (((ks << 2) | lg) ^ (rv & 7)) * 8];
            }
            ls = __builtin_amdgcn_mfma_f32_16x16x32_bf16(pa, ones, ls, 0, 0, 0);
            #pragma unroll
            for (int ni = 0; ni < 4; ++ni)
                oacc[ni] = __builtin_amdgcn_mfma_f32_16x16x32_bf16(pa, vb[ni], oacc[ni], 0, 0, 0);
        }
        #pragma unroll
        for (int r = 0; r < 4; ++r)
            lrow[r] = lrow[r] * av[r] + ls[r];

        __builtin_amdgcn_s_barrier();   // Vs free before next iteration's stage
    }

    // epilogue: ctx = O / l, bf16
    #pragma unroll
    for (int r = 0; r < 4; ++r) {
        float inv = 1.0f / lrow[r];
        int q = qw + lg * 4 + r;
        size_t base = (size_t)(b * 2048 + q) * 1024 + h * 64 + lr;
        #pragma unroll
        for (int ni = 0; ni < 4; ++ni)
            ctx[base + ni * 16] = f2bf(oacc[ni][r] * inv);
    }
}

// ---------------- output GEMM: ctx(4096x1024) @ Wo + bo -> f32 ----------------
__global__ __launch_bounds__(256, 2)
void gemm_out_kernel(const unsigned short* __restrict__ A, const unsigned short* __restrict__ Bt,
                     float* __restrict__ C, const float* __restrict__ bias) {
    __shared__ unsigned short As[128 * 64];
    __shared__ unsigned short Bs[128 * 64];
    const int tid = threadIdx.x;
    const int w = tid >> 6, l = tid & 63;
    const int lr = l & 15, lg = l >> 4;
    const int wr = w >> 1, wc = w & 1;
    const int m0 = blockIdx.y * 128;
    const int n0 = blockIdx.x * 128;
    const int K = 1024;

    f32x4 acc[4][4] = {};

    for (int k0 = 0; k0 < 1024; k0 += 64) {
        #pragma unroll
        for (int p = 0; p < 4; ++p) {
            int seg = p * 4 + w;
            int row = seg * 8 + (l >> 3);
            int c16 = (l & 7) ^ (row & 7);
            gload16(A  + (size_t)(m0 + row) * K + k0 + c16 * 8, &As[seg * 512]);
            gload16(Bt + (size_t)(n0 + row) * K + k0 + c16 * 8, &Bs[seg * 512]);
        }
        __syncthreads();
        #pragma unroll
        for (int ks = 0; ks < 2; ++ks) {
            bf16x8 af[4], bfr[4];
            #pragma unroll
            for (int i = 0; i < 4; ++i) {
                int ra = wr * 64 + i * 16 + lr;
                af[i] = *(const bf16x8*)&As[ra * 64 + (((ks << 2) | lg) ^ (ra & 7)) * 8];
                int rb = wc * 64 + i * 16 + lr;
                bfr[i] = *(const bf16x8*)&Bs[rb * 64 + (((ks << 2) | lg) ^ (rb & 7)) * 8];
            }
            #pragma unroll
            for (int i = 0; i < 4; ++i)
                #pragma unroll
                for (int j = 0; j < 4; ++j)
                    acc[i][j] = __builtin_amdgcn_mfma_f32_16x16x32_bf16(af[i], bfr[j], acc[i][j], 0, 0, 0);
        }
        __syncthreads();
    }

    #pragma unroll
    for (int i = 0; i < 4; ++i)
        #pragma unroll
        for (int j = 0; j < 4; ++j) {
            int n = n0 + wc * 64 + j * 16 + lr;
            float bv = bias[n];
            #pragma unroll
            for (int r = 0; r < 4; ++r) {
                int m = m0 + wr * 64 + i * 16 + lg * 4 + r;
                C[(size_t)m * 1024 + n] = acc[i][j][r] + bv;
            }
        }
}

extern "C" void kernel_launch(void* const* d_in, const int* in_sizes, int n_in,
                              void* d_out, int out_size, void* d_ws, size_t ws_size,
                              hipStream_t stream) {
    (void)in_sizes; (void)n_in; (void)out_size; (void)ws_size;
    const float* x  = (const float*)d_in[0];
    const float* Wq = (const float*)d_in[1];
    const float* Wk = (const float*)d_in[2];
    const float* Wv = (const float*)d_in[3];
    const float* Wo = (const float*)d_in[4];
    const float* bo = (const float*)d_in[5];
    float* out = (float*)d_out;

    char* ws = (char*)d_ws;
    const size_t MB = 1024 * 1024;
    unsigned short* xb   = (unsigned short*)(ws);            // 8 MB: x bf16 (4096x1024)
    unsigned short* Wcat = (unsigned short*)(ws + 8  * MB);  // 6 MB: [Wq;Wk;Wv]^T (3072x1024)
    unsigned short* Wot  = (unsigned short*)(ws + 14 * MB);  // 2 MB: Wo^T
    unsigned short* Qb   = (unsigned short*)(ws + 16 * MB);  // 8 MB (pre-scaled by 0.125*log2e)
    unsigned short* Kb   = (unsigned short*)(ws + 24 * MB);  // 8 MB
    unsigned short* Vtb  = (unsigned short*)(ws + 32 * MB);  // 8 MB: V^T (b,h,d,s)
    unsigned short* Cxb  = (unsigned short*)(ws + 40 * MB);  // 8 MB: ctx bf16

    cast_x_kernel<<<2048, 256, 0, stream>>>(x, xb);
    castT_w_kernel<<<dim3(32, 32, 4), 256, 0, stream>>>(Wq, Wk, Wv, Wo, Wcat, Wot);
    gemm_qkv_kernel<<<dim3(24, 32), 256, 0, stream>>>(xb, Wcat, Qb, Kb, Vtb);
    flash_attn_kernel<<<1024, 256, 0, stream>>>(Qb, Kb, Vtb, Cxb);
    gemm_out_kernel<<<dim3(8, 32), 256, 0, stream>>>(Cxb, Wot, out, bo);
}

// Round 5
// 107.527 us; speedup vs baseline: 1.5825x; 1.0667x over previous
//
#include <hip/hip_runtime.h>
#include <hip/hip_bf16.h>
#include <cstdint>

typedef __attribute__((ext_vector_type(8))) __bf16 bf16x8;
typedef __attribute__((ext_vector_type(4))) float f32x4;
typedef __attribute__((ext_vector_type(8))) unsigned short u16x8;
typedef __attribute__((ext_vector_type(4))) unsigned short u16x4;

#define NEG_INF (-__builtin_inff())

__device__ __forceinline__ unsigned short f2bf(float f) {
    unsigned int u = __builtin_bit_cast(unsigned int, f);
    u += 0x7FFFu + ((u >> 16) & 1u);
    return (unsigned short)(u >> 16);
}

__device__ __forceinline__ void gload16(const void* g, void* l) {
    __builtin_amdgcn_global_load_lds(
        (__attribute__((address_space(1))) void*)(uintptr_t)g,
        (__attribute__((address_space(3))) void*)(uint32_t)(uintptr_t)l, 16, 0, 0);
}

// ---------------- cast x (f32 -> bf16), 8 elems/thread ----------------
__global__ void cast_x_kernel(const float* __restrict__ x, unsigned short* __restrict__ xb) {
    size_t i = (size_t)blockIdx.x * 256 + threadIdx.x;
    const float4* p = (const float4*)x + i * 2;
    float4 a = p[0], c = p[1];
    u16x8 o;
    o[0] = f2bf(a.x); o[1] = f2bf(a.y); o[2] = f2bf(a.z); o[3] = f2bf(a.w);
    o[4] = f2bf(c.x); o[5] = f2bf(c.y); o[6] = f2bf(c.z); o[7] = f2bf(c.w);
    ((u16x8*)xb)[i] = o;
}

// ------------- transpose+cast weights: Wcat=[Wq;Wk;Wv]^T (3072x1024), Wot (1024x1024) -------------
__global__ void castT_w_kernel(const float* __restrict__ W0, const float* __restrict__ W1,
                               const float* __restrict__ W2, const float* __restrict__ W3,
                               unsigned short* __restrict__ Wcat, unsigned short* __restrict__ Wot) {
    __shared__ float t[32][33];
    int z = blockIdx.z;
    const float* src = (z == 0) ? W0 : (z == 1) ? W1 : (z == 2) ? W2 : W3;
    unsigned short* dst = (z < 3) ? (Wcat + (size_t)z * 1024 * 1024) : Wot;
    int n0 = blockIdx.x * 32, k0 = blockIdx.y * 32;
    int tx = threadIdx.x & 31, ty = threadIdx.x >> 5;
    #pragma unroll
    for (int i = 0; i < 4; ++i) {
        int r = ty + i * 8;
        t[r][tx] = src[(size_t)(k0 + r) * 1024 + n0 + tx];
    }
    __syncthreads();
    #pragma unroll
    for (int i = 0; i < 4; ++i) {
        int r = ty + i * 8;
        dst[(size_t)(n0 + r) * 1024 + k0 + tx] = f2bf(t[tx][r]);
    }
}

// ---------------- fused QKV GEMM: A(4096x1024) * Wcat^T rows -> Q,K row-major; V transposed ----------------
__global__ __launch_bounds__(256, 2)
void gemm_qkv_kernel(const unsigned short* __restrict__ A, const unsigned short* __restrict__ Bt,
                     unsigned short* __restrict__ Qb, unsigned short* __restrict__ Kb,
                     unsigned short* __restrict__ Vtb) {
    __shared__ unsigned short As[128 * 64];
    __shared__ unsigned short Bs[128 * 64];
    const int tid = threadIdx.x;
    const int w = tid >> 6, l = tid & 63;
    const int lr = l & 15, lg = l >> 4;
    const int wr = w >> 1, wc = w & 1;
    const int m0 = blockIdx.y * 128;
    const int n0 = blockIdx.x * 128;
    const int K = 1024;

    f32x4 acc[4][4] = {};

    for (int k0 = 0; k0 < 1024; k0 += 64) {
        #pragma unroll
        for (int p = 0; p < 4; ++p) {
            int seg = p * 4 + w;
            int row = seg * 8 + (l >> 3);
            int c16 = (l & 7) ^ (row & 7);
            gload16(A  + (size_t)(m0 + row) * K + k0 + c16 * 8, &As[seg * 512]);
            gload16(Bt + (size_t)(n0 + row) * K + k0 + c16 * 8, &Bs[seg * 512]);
        }
        __syncthreads();
        #pragma unroll
        for (int ks = 0; ks < 2; ++ks) {
            bf16x8 af[4], bfr[4];
            #pragma unroll
            for (int i = 0; i < 4; ++i) {
                int ra = wr * 64 + i * 16 + lr;
                af[i] = *(const bf16x8*)&As[ra * 64 + (((ks << 2) | lg) ^ (ra & 7)) * 8];
                int rb = wc * 64 + i * 16 + lr;
                bfr[i] = *(const bf16x8*)&Bs[rb * 64 + (((ks << 2) | lg) ^ (rb & 7)) * 8];
            }
            #pragma unroll
            for (int i = 0; i < 4; ++i)
                #pragma unroll
                for (int j = 0; j < 4; ++j)
                    acc[i][j] = __builtin_amdgcn_mfma_f32_16x16x32_bf16(af[i], bfr[j], acc[i][j], 0, 0, 0);
        }
        __syncthreads();
    }

    const int seg = n0 >> 10;        // 0=Q, 1=K, 2=V
    const int n0l = n0 & 1023;
    if (seg < 2) {
        unsigned short* C = (seg == 0) ? Qb : Kb;
        // fold 1/sqrt(64) AND log2(e) into Q so attention can use raw exp2
        const float sc = (seg == 0) ? 0.125f * 1.44269504f : 1.0f;
        #pragma unroll
        for (int i = 0; i < 4; ++i)
            #pragma unroll
            for (int j = 0; j < 4; ++j) {
                int n = n0l + wc * 64 + j * 16 + lr;
                #pragma unroll
                for (int r = 0; r < 4; ++r) {
                    int m = m0 + wr * 64 + i * 16 + lg * 4 + r;
                    C[(size_t)m * 1024 + n] = f2bf(acc[i][j][r] * sc);
                }
            }
    } else {
        // V transposed: Vt[(b*1024 + n)*2048 + s], m = b*2048+s
        #pragma unroll
        for (int i = 0; i < 4; ++i)
            #pragma unroll
            for (int j = 0; j < 4; ++j) {
                int n = n0l + wc * 64 + j * 16 + lr;
                int mb = m0 + wr * 64 + i * 16 + lg * 4;
                int bb = mb >> 11, s = mb & 2047;
                u16x4 o;
                #pragma unroll
                for (int r = 0; r < 4; ++r) o[r] = f2bf(acc[i][j][r]);
                *(u16x4*)&Vtb[((size_t)(bb * 1024 + n)) * 2048 + s] = o;
            }
    }
}

// ---------------- flash attention (causal) v5: swapped QK^T ----------------
// 256-thread blocks (4 waves x 16 q-rows, QBLK=64), KVBLK=64.
// mfma(K,Q) puts each lane on ONE q-row (q=qw+lr): row max = local tree + 2
// shuffles; row sum rides the exp2 loop (ones-MFMA deleted); m/l/av are scalars.
// K double-buffered + counted vmcnt; grid 1024, complementary qs decode.
__global__ __launch_bounds__(256, 4)
void flash_attn_kernel(const unsigned short* __restrict__ Q, const unsigned short* __restrict__ Kg,
                       const unsigned short* __restrict__ Vt, unsigned short* __restrict__ ctx) {
    __shared__ unsigned short Ks[2][4096];
    __shared__ unsigned short Vs[4096];
    __shared__ unsigned short Ps[4][1152];
    const int tid = threadIdx.x, w = tid >> 6, l = tid & 63;
    const int lr = l & 15, lg = l >> 4;

    // decode: ids {c, c+256, c+512, c+768} -> qs {g, 31-g, 8+g, 23-g} (T-sum 66 per CU)
    const int id = blockIdx.x;
    const int s = id >> 5;
    const int bh = id & 31;
    const int g = s & 7, hi = s >> 3;
    const int qs = (hi & 1) ? (31 - (g + (hi >> 1) * 8)) : (g + (hi >> 1) * 8);
    const int b = bh >> 4, h = bh & 15;
    const int qw = qs * 64 + w * 16;
    const int T = qs + 1;

    const int srow8 = w * 8 + (l >> 3);     // row within each 32-row staging round
    const int scol  = (l & 7) ^ (srow8 & 7);
    const unsigned short* Kbase = Kg + (size_t)(b * 2048) * 1024 + h * 64;
    const unsigned short* Vbase = Vt + (size_t)(b * 1024 + h * 64) * 2048;

    // Q fragments (pre-scaled by 0.125*log2e); used as the B operand
    bf16x8 qf[2];
    #pragma unroll
    for (int ks = 0; ks < 2; ++ks)
        qf[ks] = *(const bf16x8*)&Q[(size_t)(b * 2048 + qw + lr) * 1024 + h * 64 + ks * 32 + lg * 8];

    float mrow = NEG_INF, lrow = 0.0f;
    f32x4 oacc[4] = {};

    // prologue: stage K(0) into buf 0 (2 loads/thread)
    #pragma unroll
    for (int p = 0; p < 2; ++p)
        gload16(Kbase + (size_t)(p * 32 + srow8) * 1024 + scol * 8, &Ks[0][(p * 32 + w * 8) * 64]);

    for (int t = 0; t < T; ++t) {
        const int cur = t & 1;
        const int k0 = t * 64;
        // issue V(t), then K(t+1) into the other K buffer
        #pragma unroll
        for (int p = 0; p < 2; ++p)
            gload16(Vbase + (size_t)(p * 32 + srow8) * 2048 + k0 + scol * 8, &Vs[(p * 32 + w * 8) * 64]);
        const int ktn = (t + 1 < T) ? t + 1 : 0;   // dummy reload keeps vmcnt pattern constant
        #pragma unroll
        for (int p = 0; p < 2; ++p)
            gload16(Kbase + (size_t)(ktn * 64 + p * 32 + srow8) * 1024 + scol * 8, &Ks[cur ^ 1][(p * 32 + w * 8) * 64]);

        asm volatile("s_waitcnt vmcnt(4)" ::: "memory");   // K(t) resident; V(t)+K(t+1) in flight
        __builtin_amdgcn_s_barrier();

        // ---- S^T tile via mfma(K, Q): sf[ni][r] = S[q=qw+lr][k = k0+ni*16+lg*4+r] ----
        f32x4 sf[4] = {};
        #pragma unroll
        for (int ks = 0; ks < 2; ++ks) {
            bf16x8 kf[4];
            #pragma unroll
            for (int ni = 0; ni < 4; ++ni) {
                int rk = ni * 16 + lr;
                kf[ni] = *(const bf16x8*)&Ks[cur][rk * 64 + (((ks << 2) | lg) ^ (rk & 7)) * 8];
            }
            #pragma unroll
            for (int ni = 0; ni < 4; ++ni)
                sf[ni] = __builtin_amdgcn_mfma_f32_16x16x32_bf16(kf[ni], qf[ks], sf[ni], 0, 0, 0);
        }
        // ---- causal mask (diagonal tile only): k > q -> -inf ----
        if (t == T - 1) {
            #pragma unroll
            for (int ni = 0; ni < 4; ++ni)
                #pragma unroll
                for (int r = 0; r < 4; ++r)
                    if (k0 + ni * 16 + lg * 4 + r > qw + lr) sf[ni][r] = NEG_INF;
        }
        // ---- online softmax: per-lane q-row; local tree max + 2 shuffles ----
        float vmax = fmaxf(fmaxf(fmaxf(sf[0][0], sf[0][1]), fmaxf(sf[0][2], sf[0][3])),
                           fmaxf(fmaxf(sf[1][0], sf[1][1]), fmaxf(sf[1][2], sf[1][3])));
        vmax = fmaxf(vmax, fmaxf(fmaxf(fmaxf(sf[2][0], sf[2][1]), fmaxf(sf[2][2], sf[2][3])),
                                 fmaxf(fmaxf(sf[3][0], sf[3][1]), fmaxf(sf[3][2], sf[3][3]))));
        vmax = fmaxf(vmax, __shfl_xor(vmax, 16));
        vmax = fmaxf(vmax, __shfl_xor(vmax, 32));
        float mn = fmaxf(mrow, vmax);
        float av = __builtin_amdgcn_exp2f(mrow - mn);
        mrow = mn;
        float rs = 0.0f;
        #pragma unroll
        for (int ni = 0; ni < 4; ++ni) {
            u16x4 pw;
            #pragma unroll
            for (int r = 0; r < 4; ++r) {
                float pv = __builtin_amdgcn_exp2f(sf[ni][r] - mn);
                rs += pv;
                pw[r] = f2bf(pv);
            }
            *(u16x4*)&Ps[w][lr * 72 + ni * 16 + lg * 4] = pw;
        }
        rs += __shfl_xor(rs, 16);
        rs += __shfl_xor(rs, 32);
        lrow = lrow * av + rs;
        // redistribute av to PV C-layout rows (row q = qw + lg*4 + r)
        float avr[4];
        #pragma unroll
        for (int r = 0; r < 4; ++r) avr[r] = __shfl(av, lg * 4 + r);
        #pragma unroll
        for (int ni = 0; ni < 4; ++ni)
            #pragma unroll
            for (int r = 0; r < 4; ++r)
                oacc[ni][r] *= avr[r];

        asm volatile("s_waitcnt vmcnt(2)" ::: "memory");   // V(t) resident; K(t+1) in flight
        __builtin_amdgcn_s_barrier();

        // ---- O += P V ----
        #pragma unroll
        for (int ks = 0; ks < 2; ++ks) {
            bf16x8 pa = *(const bf16x8*)&Ps[w][lr * 72 + ks * 32 + lg * 8];
            bf16x8 vb[4];
            #pragma unroll
            for (int ni = 0; ni < 4; ++ni) {
                int rv = ni * 16 + lr;
                vb[ni] = *(const bf16x8*)&Vs[rv * 64 + (((ks << 2) | lg) ^ (rv & 7)) * 8];
            }
            #pragma unroll
            for (int ni = 0; ni < 4; ++ni)
                oacc[ni] = __builtin_amdgcn_mfma_f32_16x16x32_bf16(pa, vb[ni], oacc[ni], 0, 0, 0);
        }

        __builtin_amdgcn_s_barrier();   // Vs free before next iteration's stage
    }

    // epilogue: ctx = O / l, bf16  (lrow redistributed to C-layout rows)
    float lr4[4];
    #pragma unroll
    for (int r = 0; r < 4; ++r) lr4[r] = __shfl(lrow, lg * 4 + r);
    #pragma unroll
    for (int r = 0; r < 4; ++r) {
        float inv = 1.0f / lr4[r];
        int q = qw + lg * 4 + r;
        size_t base = (size_t)(b * 2048 + q) * 1024 + h * 64 + lr;
        #pragma unroll
        for (int ni = 0; ni < 4; ++ni)
            ctx[base + ni * 16] = f2bf(oacc[ni][r] * inv);
    }
}

// ---------------- output GEMM: ctx(4096x1024) @ Wo + bo -> f32 ----------------
__global__ __launch_bounds__(256, 2)
void gemm_out_kernel(const unsigned short* __restrict__ A, const unsigned short* __restrict__ Bt,
                     float* __restrict__ C, const float* __restrict__ bias) {
    __shared__ unsigned short As[128 * 64];
    __shared__ unsigned short Bs[128 * 64];
    const int tid = threadIdx.x;
    const int w = tid >> 6, l = tid & 63;
    const int lr = l & 15, lg = l >> 4;
    const int wr = w >> 1, wc = w & 1;
    const int m0 = blockIdx.y * 128;
    const int n0 = blockIdx.x * 128;
    const int K = 1024;

    f32x4 acc[4][4] = {};

    for (int k0 = 0; k0 < 1024; k0 += 64) {
        #pragma unroll
        for (int p = 0; p < 4; ++p) {
            int seg = p * 4 + w;
            int row = seg * 8 + (l >> 3);
            int c16 = (l & 7) ^ (row & 7);
            gload16(A  + (size_t)(m0 + row) * K + k0 + c16 * 8, &As[seg * 512]);
            gload16(Bt + (size_t)(n0 + row) * K + k0 + c16 * 8, &Bs[seg * 512]);
        }
        __syncthreads();
        #pragma unroll
        for (int ks = 0; ks < 2; ++ks) {
            bf16x8 af[4], bfr[4];
            #pragma unroll
            for (int i = 0; i < 4; ++i) {
                int ra = wr * 64 + i * 16 + lr;
                af[i] = *(const bf16x8*)&As[ra * 64 + (((ks << 2) | lg) ^ (ra & 7)) * 8];
                int rb = wc * 64 + i * 16 + lr;
                bfr[i] = *(const bf16x8*)&Bs[rb * 64 + (((ks << 2) | lg) ^ (rb & 7)) * 8];
            }
            #pragma unroll
            for (int i = 0; i < 4; ++i)
                #pragma unroll
                for (int j = 0; j < 4; ++j)
                    acc[i][j] = __builtin_amdgcn_mfma_f32_16x16x32_bf16(af[i], bfr[j], acc[i][j], 0, 0, 0);
        }
        __syncthreads();
    }

    #pragma unroll
    for (int i = 0; i < 4; ++i)
        #pragma unroll
        for (int j = 0; j < 4; ++j) {
            int n = n0 + wc * 64 + j * 16 + lr;
            float bv = bias[n];
            #pragma unroll
            for (int r = 0; r < 4; ++r) {
                int m = m0 + wr * 64 + i * 16 + lg * 4 + r;
                C[(size_t)m * 1024 + n] = acc[i][j][r] + bv;
            }
        }
}

extern "C" void kernel_launch(void* const* d_in, const int* in_sizes, int n_in,
                              void* d_out, int out_size, void* d_ws, size_t ws_size,
                              hipStream_t stream) {
    (void)in_sizes; (void)n_in; (void)out_size; (void)ws_size;
    const float* x  = (const float*)d_in[0];
    const float* Wq = (const float*)d_in[1];
    const float* Wk = (const float*)d_in[2];
    const float* Wv = (const float*)d_in[3];
    const float* Wo = (const float*)d_in[4];
    const float* bo = (const float*)d_in[5];
    float* out = (float*)d_out;

    char* ws = (char*)d_ws;
    const size_t MB = 1024 * 1024;
    unsigned short* xb   = (unsigned short*)(ws);            // 8 MB: x bf16 (4096x1024)
    unsigned short* Wcat = (unsigned short*)(ws + 8  * MB);  // 6 MB: [Wq;Wk;Wv]^T (3072x1024)
    unsigned short* Wot  = (unsigned short*)(ws + 14 * MB);  // 2 MB: Wo^T
    unsigned short* Qb   = (unsigned short*)(ws + 16 * MB);  // 8 MB (pre-scaled by 0.125*log2e)
    unsigned short* Kb   = (unsigned short*)(ws + 24 * MB);  // 8 MB
    unsigned short* Vtb  = (unsigned short*)(ws + 32 * MB);  // 8 MB: V^T (b,h,d,s)
    unsigned short* Cxb  = (unsigned short*)(ws + 40 * MB);  // 8 MB: ctx bf16

    cast_x_kernel<<<2048, 256, 0, stream>>>(x, xb);
    castT_w_kernel<<<dim3(32, 32, 4), 256, 0, stream>>>(Wq, Wk, Wv, Wo, Wcat, Wot);
    gemm_qkv_kernel<<<dim3(24, 32), 256, 0, stream>>>(xb, Wcat, Qb, Kb, Vtb);
    flash_attn_kernel<<<1024, 256, 0, stream>>>(Qb, Kb, Vtb, Cxb);
    gemm_out_kernel<<<dim3(8, 32), 256, 0, stream>>>(Cxb, Wot, out, bo);
}